// Round 1
// baseline (1069.095 us; speedup 1.0000x reference)
//
#include <hip/hip_runtime.h>
#include <hip/hip_bf16.h>

// Segment-sum: out[seg, f] += edge_w[e, f] for seg = edge[dim==1 ? 0 : 1][e].
// E = 1.25M, F = 64, N = 50K. Memory-bound: ~338 MB traffic.
// 16 threads per edge, each handling 4 contiguous floats (float4 load + 4 atomicAdd).

#define F_DIM 64

__global__ void Edge2Node_40346922779128_kernel(
    const int* __restrict__ edge,      // [2, E]
    const float* __restrict__ edge_w,  // [E, 64]
    const int* __restrict__ dim_p,     // scalar
    float* __restrict__ out,           // [N, 64]
    int E)
{
    const int dim = *dim_p;                 // uniform, L1-cached
    const int row = (dim == 1) ? 0 : 1;
    const long long total = (long long)E * 16;   // 16 threads per edge
    const long long stride = (long long)gridDim.x * blockDim.x;
    for (long long i = (long long)blockIdx.x * blockDim.x + threadIdx.x;
         i < total; i += stride) {
        const int e = (int)(i >> 4);
        const int c = ((int)i & 15) << 2;           // feature offset 0..60 step 4
        const int seg = edge[(long long)row * E + e];
        const float4 v = *reinterpret_cast<const float4*>(
            edge_w + (long long)e * F_DIM + c);
        float* o = out + (long long)seg * F_DIM + c;
        atomicAdd(o + 0, v.x);
        atomicAdd(o + 1, v.y);
        atomicAdd(o + 2, v.z);
        atomicAdd(o + 3, v.w);
    }
}

extern "C" void kernel_launch(void* const* d_in, const int* in_sizes, int n_in,
                              void* d_out, int out_size, void* d_ws, size_t ws_size,
                              hipStream_t stream) {
    const int*   edge   = (const int*)d_in[0];
    const float* edge_w = (const float*)d_in[1];
    const int*   dim_p  = (const int*)d_in[5];
    float*       out    = (float*)d_out;

    const int E = in_sizes[0] / 2;

    // Zero output every call: atomics accumulate and the harness does not
    // re-poison between graph replays.
    hipMemsetAsync(d_out, 0, (size_t)out_size * sizeof(float), stream);

    const int block = 256;
    const int grid  = 2048;  // grid-stride; ~38 iters/thread
    Edge2Node_40346922779128_kernel<<<grid, block, 0, stream>>>(
        edge, edge_w, dim_p, out, E);
}

// Round 2
// 359.878 us; speedup vs baseline: 2.9707x; 2.9707x over previous
//
#include <hip/hip_runtime.h>
#include <hip/hip_bf16.h>

// Segment-sum via CSR build + atomic-free gather.
// out[seg, f] = sum over edges e with edge[row][e]==seg of edge_w[e, f].
// row = 0 if dim==1 else 1 (read on device; host never sees dim's value).

#define F_DIM 64

// ---------- phase 1: histogram ----------
__global__ void hist_kernel(const int* __restrict__ edge,
                            const int* __restrict__ dim_p,
                            int* __restrict__ counts, int E) {
    const int row = (*dim_p == 1) ? 0 : 1;
    const int stride = gridDim.x * blockDim.x;
    for (int e = blockIdx.x * blockDim.x + threadIdx.x; e < E; e += stride)
        atomicAdd(&counts[edge[(size_t)row * E + e]], 1);
}

// ---------- phase 2: exclusive scan (single block, 1024 threads) ----------
__global__ void scan_kernel(const int* __restrict__ counts,
                            int* __restrict__ offsets,
                            int* __restrict__ cursor, int N) {
    __shared__ int s[1024];
    const int t = threadIdx.x;
    const int chunk = (N + 1023) / 1024;
    const int beg = t * chunk;
    const int end = min(beg + chunk, N);
    int local = 0;
    for (int i = beg; i < end; ++i) local += counts[i];
    s[t] = local;
    __syncthreads();
    // Hillis-Steele inclusive scan over the 1024 partial sums
    for (int d = 1; d < 1024; d <<= 1) {
        int v = (t >= d) ? s[t - d] : 0;
        __syncthreads();
        s[t] += v;
        __syncthreads();
    }
    int run = s[t] - local;  // exclusive prefix of this thread's chunk
    for (int i = beg; i < end; ++i) {
        offsets[i] = run;
        cursor[i]  = run;
        run += counts[i];
    }
    if (t == 1023) offsets[N] = run;  // == E
}

// ---------- phase 3: scatter edge ids into CSR order ----------
__global__ void scatter_kernel(const int* __restrict__ edge,
                               const int* __restrict__ dim_p,
                               int* __restrict__ cursor,
                               int* __restrict__ perm, int E) {
    const int row = (*dim_p == 1) ? 0 : 1;
    const int stride = gridDim.x * blockDim.x;
    for (int e = blockIdx.x * blockDim.x + threadIdx.x; e < E; e += stride) {
        const int seg = edge[(size_t)row * E + e];
        const int pos = atomicAdd(&cursor[seg], 1);
        perm[pos] = e;
    }
}

// ---------- phase 4: gather-reduce, one wave per node ----------
__global__ void gather_kernel(const float* __restrict__ edge_w,
                              const int* __restrict__ offsets,
                              const int* __restrict__ perm,
                              float* __restrict__ out, int N) {
    const int node = blockIdx.x * (blockDim.x >> 6) + (threadIdx.x >> 6);
    const int lane = threadIdx.x & 63;
    if (node >= N) return;
    const int beg = offsets[node];
    const int end = offsets[node + 1];
    float acc = 0.0f;
    int j = beg;
    // unroll by 4: issue 4 independent perm loads, then 4 gathers
    for (; j + 4 <= end; j += 4) {
        const int e0 = perm[j + 0];
        const int e1 = perm[j + 1];
        const int e2 = perm[j + 2];
        const int e3 = perm[j + 3];
        const float a0 = edge_w[(size_t)e0 * F_DIM + lane];
        const float a1 = edge_w[(size_t)e1 * F_DIM + lane];
        const float a2 = edge_w[(size_t)e2 * F_DIM + lane];
        const float a3 = edge_w[(size_t)e3 * F_DIM + lane];
        acc += a0; acc += a1; acc += a2; acc += a3;
    }
    for (; j < end; ++j)
        acc += edge_w[(size_t)perm[j] * F_DIM + lane];
    out[(size_t)node * F_DIM + lane] = acc;
}

// ---------- fallback: direct atomic scatter (if workspace too small) ----------
__global__ void atomic_kernel(const int* __restrict__ edge,
                              const float* __restrict__ edge_w,
                              const int* __restrict__ dim_p,
                              float* __restrict__ out, int E) {
    const int dim = *dim_p;
    const int row = (dim == 1) ? 0 : 1;
    const long long total = (long long)E * 16;
    const long long stride = (long long)gridDim.x * blockDim.x;
    for (long long i = (long long)blockIdx.x * blockDim.x + threadIdx.x;
         i < total; i += stride) {
        const int e = (int)(i >> 4);
        const int c = ((int)i & 15) << 2;
        const int seg = edge[(long long)row * E + e];
        const float4 v = *reinterpret_cast<const float4*>(
            edge_w + (long long)e * F_DIM + c);
        float* o = out + (long long)seg * F_DIM + c;
        atomicAdd(o + 0, v.x);
        atomicAdd(o + 1, v.y);
        atomicAdd(o + 2, v.z);
        atomicAdd(o + 3, v.w);
    }
}

extern "C" void kernel_launch(void* const* d_in, const int* in_sizes, int n_in,
                              void* d_out, int out_size, void* d_ws, size_t ws_size,
                              hipStream_t stream) {
    const int*   edge   = (const int*)d_in[0];
    const float* edge_w = (const float*)d_in[1];
    const int*   dim_p  = (const int*)d_in[5];
    float*       out    = (float*)d_out;

    const int E = in_sizes[0] / 2;
    const int F = in_sizes[1] / E;           // 64
    const int N = out_size / F;              // 50000

    // workspace layout (ints): counts[N] | offsets[N+1] | cursor[N] | perm[E]
    const size_t need = ((size_t)4 * N + 1 + (size_t)E) * sizeof(int);
    if (ws_size < need) {
        // fallback: known-correct atomic path
        hipMemsetAsync(d_out, 0, (size_t)out_size * sizeof(float), stream);
        atomic_kernel<<<2048, 256, 0, stream>>>(edge, edge_w, dim_p, out, E);
        return;
    }

    int* counts  = (int*)d_ws;
    int* offsets = counts + N;
    int* cursor  = offsets + N + 1;
    int* perm    = cursor + N;

    hipMemsetAsync(counts, 0, (size_t)N * sizeof(int), stream);

    const int block = 256;
    const int gridE = min(2048, (E + block - 1) / block);

    hist_kernel<<<gridE, block, 0, stream>>>(edge, dim_p, counts, E);
    scan_kernel<<<1, 1024, 0, stream>>>(counts, offsets, cursor, N);
    scatter_kernel<<<gridE, block, 0, stream>>>(edge, dim_p, cursor, perm, E);

    const int nodes_per_block = block / 64;                  // 4
    const int gridN = (N + nodes_per_block - 1) / nodes_per_block;
    gather_kernel<<<gridN, block, 0, stream>>>(edge_w, offsets, perm, out, N);
}

// Round 3
// 338.310 us; speedup vs baseline: 3.1601x; 1.0638x over previous
//
#include <hip/hip_runtime.h>
#include <hip/hip_bf16.h>

// Segment-sum via CSR build + atomic-free gather.
// out[seg, f] = sum over edges e with edge[row][e]==seg of edge_w[e, f].
// row = 0 if dim==1 else 1 (read on device).
//
// R2 changes: (1) custom zero kernel replaces hipMemsetAsync(counts) -- the
// runtime fillBufferAligned for 200KB cost 186us (52% of total) in the graph.
// (2) gather uses 4 edge-groups x 16 lanes x float4 for 4x MLP, folded with
// two shfl_xor steps.

#define F_DIM 64

// ---------- phase 0: zero the counts ----------
__global__ void zero_kernel(int* __restrict__ counts, int N) {
    const int i = blockIdx.x * blockDim.x + threadIdx.x;
    if (i < N) counts[i] = 0;
}

// ---------- phase 1: histogram ----------
__global__ void hist_kernel(const int* __restrict__ edge,
                            const int* __restrict__ dim_p,
                            int* __restrict__ counts, int E) {
    const int row = (*dim_p == 1) ? 0 : 1;
    const int stride = gridDim.x * blockDim.x;
    for (int e = blockIdx.x * blockDim.x + threadIdx.x; e < E; e += stride)
        atomicAdd(&counts[edge[(size_t)row * E + e]], 1);
}

// ---------- phase 2: exclusive scan (single block, 1024 threads) ----------
__global__ void scan_kernel(const int* __restrict__ counts,
                            int* __restrict__ offsets,
                            int* __restrict__ cursor, int N) {
    __shared__ int s[1024];
    const int t = threadIdx.x;
    const int chunk = (N + 1023) / 1024;
    const int beg = t * chunk;
    const int end = min(beg + chunk, N);
    int local = 0;
    for (int i = beg; i < end; ++i) local += counts[i];
    s[t] = local;
    __syncthreads();
    for (int d = 1; d < 1024; d <<= 1) {
        int v = (t >= d) ? s[t - d] : 0;
        __syncthreads();
        s[t] += v;
        __syncthreads();
    }
    int run = s[t] - local;  // exclusive prefix of this thread's chunk
    for (int i = beg; i < end; ++i) {
        offsets[i] = run;
        cursor[i]  = run;
        run += counts[i];
    }
    if (t == 1023) offsets[N] = run;  // == E
}

// ---------- phase 3: scatter edge ids into CSR order ----------
__global__ void scatter_kernel(const int* __restrict__ edge,
                               const int* __restrict__ dim_p,
                               int* __restrict__ cursor,
                               int* __restrict__ perm, int E) {
    const int row = (*dim_p == 1) ? 0 : 1;
    const int stride = gridDim.x * blockDim.x;
    for (int e = blockIdx.x * blockDim.x + threadIdx.x; e < E; e += stride) {
        const int seg = edge[(size_t)row * E + e];
        const int pos = atomicAdd(&cursor[seg], 1);
        perm[pos] = e;
    }
}

// ---------- phase 4: gather-reduce, one wave per node ----------
// 4 groups of 16 lanes; group g processes edge j+g; lane loads float4.
__global__ __launch_bounds__(256) void gather_kernel(
    const float* __restrict__ edge_w,
    const int* __restrict__ offsets,
    const int* __restrict__ perm,
    float* __restrict__ out, int N) {
    const int node = blockIdx.x * (blockDim.x >> 6) + (threadIdx.x >> 6);
    const int lane = threadIdx.x & 63;
    if (node >= N) return;
    const int beg = offsets[node];
    const int end = offsets[node + 1];
    const int grp = lane >> 4;           // 0..3 : which edge in the 4-batch
    const int col = (lane & 15) << 2;    // feature offset 0..60 step 4
    float4 acc = make_float4(0.f, 0.f, 0.f, 0.f);
    for (int j = beg + grp; j < end; j += 4) {
        const int e = perm[j];           // broadcast within 16-lane group
        const float4 v = *reinterpret_cast<const float4*>(
            edge_w + (size_t)e * F_DIM + col);
        acc.x += v.x; acc.y += v.y; acc.z += v.z; acc.w += v.w;
    }
    // fold the 4 edge-groups (lanes l, l^16, l^32, l^48 share feature cols)
    acc.x += __shfl_xor(acc.x, 16); acc.y += __shfl_xor(acc.y, 16);
    acc.z += __shfl_xor(acc.z, 16); acc.w += __shfl_xor(acc.w, 16);
    acc.x += __shfl_xor(acc.x, 32); acc.y += __shfl_xor(acc.y, 32);
    acc.z += __shfl_xor(acc.z, 32); acc.w += __shfl_xor(acc.w, 32);
    if (grp == 0)
        *reinterpret_cast<float4*>(out + (size_t)node * F_DIM + col) = acc;
}

// ---------- fallback: direct atomic scatter (if workspace too small) ----------
__global__ void atomic_kernel(const int* __restrict__ edge,
                              const float* __restrict__ edge_w,
                              const int* __restrict__ dim_p,
                              float* __restrict__ out, int E) {
    const int row = (*dim_p == 1) ? 0 : 1;
    const long long total = (long long)E * 16;
    const long long stride = (long long)gridDim.x * blockDim.x;
    for (long long i = (long long)blockIdx.x * blockDim.x + threadIdx.x;
         i < total; i += stride) {
        const int e = (int)(i >> 4);
        const int c = ((int)i & 15) << 2;
        const int seg = edge[(long long)row * E + e];
        const float4 v = *reinterpret_cast<const float4*>(
            edge_w + (long long)e * F_DIM + c);
        float* o = out + (long long)seg * F_DIM + c;
        atomicAdd(o + 0, v.x);
        atomicAdd(o + 1, v.y);
        atomicAdd(o + 2, v.z);
        atomicAdd(o + 3, v.w);
    }
}

extern "C" void kernel_launch(void* const* d_in, const int* in_sizes, int n_in,
                              void* d_out, int out_size, void* d_ws, size_t ws_size,
                              hipStream_t stream) {
    const int*   edge   = (const int*)d_in[0];
    const float* edge_w = (const float*)d_in[1];
    const int*   dim_p  = (const int*)d_in[5];
    float*       out    = (float*)d_out;

    const int E = in_sizes[0] / 2;
    const int F = in_sizes[1] / E;           // 64
    const int N = out_size / F;              // 50000

    // workspace layout (ints): counts[N] | offsets[N+1] | cursor[N] | perm[E]
    const size_t need = ((size_t)4 * N + 1 + (size_t)E) * sizeof(int);
    if (ws_size < need) {
        hipMemsetAsync(d_out, 0, (size_t)out_size * sizeof(float), stream);
        atomic_kernel<<<2048, 256, 0, stream>>>(edge, edge_w, dim_p, out, E);
        return;
    }

    int* counts  = (int*)d_ws;
    int* offsets = counts + N;
    int* cursor  = offsets + N + 1;
    int* perm    = cursor + N;

    const int block = 256;
    const int gridE = min(2048, (E + block - 1) / block);

    zero_kernel<<<(N + block - 1) / block, block, 0, stream>>>(counts, N);
    hist_kernel<<<gridE, block, 0, stream>>>(edge, dim_p, counts, E);
    scan_kernel<<<1, 1024, 0, stream>>>(counts, offsets, cursor, N);
    scatter_kernel<<<gridE, block, 0, stream>>>(edge, dim_p, cursor, perm, E);

    const int nodes_per_block = block / 64;                  // 4
    const int gridN = (N + nodes_per_block - 1) / nodes_per_block;
    gather_kernel<<<gridN, block, 0, stream>>>(edge_w, offsets, perm, out, N);
}

// Round 4
// 226.658 us; speedup vs baseline: 4.7168x; 1.4926x over previous
//
#include <hip/hip_runtime.h>
#include <hip/hip_bf16.h>

// Segment-sum via CSR build + atomic-free gather.
// out[seg, f] = sum over edges e with edge[row][e]==seg of edge_w[e, f].
// row = 0 if dim==1 else 1 (read on device).
//
// R3: (1) 3-kernel coalesced multi-block scan replaces the single-block
// chunked scan (1 CU, uncoalesced). (2) gather uses 8 edge-groups x 8 lanes
// x 32B with software-pipelined perm prefetch (2KB in flight per wave).

#define F_DIM 64

// ---------- zero counts ----------
__global__ void zero_kernel(int* __restrict__ counts, int N) {
    const int i = blockIdx.x * blockDim.x + threadIdx.x;
    if (i < N) counts[i] = 0;
}

// ---------- histogram ----------
__global__ void hist_kernel(const int* __restrict__ edge,
                            const int* __restrict__ dim_p,
                            int* __restrict__ counts, int E) {
    const int row = (*dim_p == 1) ? 0 : 1;
    const int stride = gridDim.x * blockDim.x;
    for (int e = blockIdx.x * blockDim.x + threadIdx.x; e < E; e += stride)
        atomicAdd(&counts[edge[(size_t)row * E + e]], 1);
}

// ---------- scan A: per-block exclusive scan + block totals ----------
__global__ void scanA_kernel(const int* __restrict__ counts,
                             int* __restrict__ offsets,
                             int* __restrict__ partials, int N) {
    __shared__ int s[256];
    const int t = threadIdx.x;
    const int idx = blockIdx.x * 256 + t;
    const int v = (idx < N) ? counts[idx] : 0;
    s[t] = v;
    __syncthreads();
    for (int d = 1; d < 256; d <<= 1) {
        const int x = (t >= d) ? s[t - d] : 0;
        __syncthreads();
        s[t] += x;
        __syncthreads();
    }
    if (idx < N) offsets[idx] = s[t] - v;      // block-local exclusive
    if (t == 255) partials[blockIdx.x] = s[255];
}

// ---------- scan B: exclusive scan of block totals (NB <= 256) ----------
__global__ void scanB_kernel(int* __restrict__ partials, int NB) {
    __shared__ int s[256];
    const int t = threadIdx.x;
    const int v = (t < NB) ? partials[t] : 0;
    s[t] = v;
    __syncthreads();
    for (int d = 1; d < 256; d <<= 1) {
        const int x = (t >= d) ? s[t - d] : 0;
        __syncthreads();
        s[t] += x;
        __syncthreads();
    }
    if (t < NB) partials[t] = s[t] - v;        // exclusive
}

// ---------- scan C: apply block prefix, init cursor, offsets[N]=E ----------
__global__ void scanC_kernel(int* __restrict__ offsets,
                             int* __restrict__ cursor,
                             const int* __restrict__ partials, int N, int E) {
    const int idx = blockIdx.x * 256 + threadIdx.x;
    if (idx < N) {
        const int off = offsets[idx] + partials[blockIdx.x];
        offsets[idx] = off;
        cursor[idx]  = off;
    }
    if (idx == 0) offsets[N] = E;
}

// ---------- scatter edge ids into CSR order ----------
__global__ void scatter_kernel(const int* __restrict__ edge,
                               const int* __restrict__ dim_p,
                               int* __restrict__ cursor,
                               int* __restrict__ perm, int E) {
    const int row = (*dim_p == 1) ? 0 : 1;
    const int stride = gridDim.x * blockDim.x;
    for (int e = blockIdx.x * blockDim.x + threadIdx.x; e < E; e += stride) {
        const int seg = edge[(size_t)row * E + e];
        const int pos = atomicAdd(&cursor[seg], 1);
        perm[pos] = e;
    }
}

// ---------- gather-reduce: one wave per node ----------
// 8 groups of 8 lanes; group g handles edge j+g; lane loads 32B (2x float4).
// perm for the next iteration is prefetched to overlap latency.
__global__ __launch_bounds__(256) void gather_kernel(
    const float* __restrict__ edge_w,
    const int* __restrict__ offsets,
    const int* __restrict__ perm,
    float* __restrict__ out, int N) {
    const int node = blockIdx.x * 4 + (threadIdx.x >> 6);
    const int lane = threadIdx.x & 63;
    if (node >= N) return;
    const int beg = offsets[node];
    const int end = offsets[node + 1];
    const int grp = lane >> 3;            // 0..7 : edge slot in the 8-batch
    const int sub = (lane & 7) << 3;      // feature offset 0..56 step 8
    float4 a0 = make_float4(0.f, 0.f, 0.f, 0.f);
    float4 a1 = make_float4(0.f, 0.f, 0.f, 0.f);
    int j = beg + grp;
    int e = (j < end) ? perm[j] : 0;
    while (j < end) {
        const int jn = j + 8;
        const int en = (jn < end) ? perm[jn] : 0;   // prefetch next perm
        const float* p = edge_w + (size_t)e * F_DIM + sub;
        const float4 v0 = *reinterpret_cast<const float4*>(p);
        const float4 v1 = *reinterpret_cast<const float4*>(p + 4);
        a0.x += v0.x; a0.y += v0.y; a0.z += v0.z; a0.w += v0.w;
        a1.x += v1.x; a1.y += v1.y; a1.z += v1.z; a1.w += v1.w;
        j = jn; e = en;
    }
    // fold the 8 edge-groups (lanes l, l^8, l^16, ... share feature cols)
    #pragma unroll
    for (int m = 8; m < 64; m <<= 1) {
        a0.x += __shfl_xor(a0.x, m); a0.y += __shfl_xor(a0.y, m);
        a0.z += __shfl_xor(a0.z, m); a0.w += __shfl_xor(a0.w, m);
        a1.x += __shfl_xor(a1.x, m); a1.y += __shfl_xor(a1.y, m);
        a1.z += __shfl_xor(a1.z, m); a1.w += __shfl_xor(a1.w, m);
    }
    if (grp == 0) {
        float* o = out + (size_t)node * F_DIM + sub;
        *reinterpret_cast<float4*>(o)     = a0;
        *reinterpret_cast<float4*>(o + 4) = a1;
    }
}

// ---------- fallback: direct atomic scatter ----------
__global__ void atomic_kernel(const int* __restrict__ edge,
                              const float* __restrict__ edge_w,
                              const int* __restrict__ dim_p,
                              float* __restrict__ out, int E) {
    const int row = (*dim_p == 1) ? 0 : 1;
    const long long total = (long long)E * 16;
    const long long stride = (long long)gridDim.x * blockDim.x;
    for (long long i = (long long)blockIdx.x * blockDim.x + threadIdx.x;
         i < total; i += stride) {
        const int e = (int)(i >> 4);
        const int c = ((int)i & 15) << 2;
        const int seg = edge[(long long)row * E + e];
        const float4 v = *reinterpret_cast<const float4*>(
            edge_w + (long long)e * F_DIM + c);
        float* o = out + (long long)seg * F_DIM + c;
        atomicAdd(o + 0, v.x);
        atomicAdd(o + 1, v.y);
        atomicAdd(o + 2, v.z);
        atomicAdd(o + 3, v.w);
    }
}

extern "C" void kernel_launch(void* const* d_in, const int* in_sizes, int n_in,
                              void* d_out, int out_size, void* d_ws, size_t ws_size,
                              hipStream_t stream) {
    const int*   edge   = (const int*)d_in[0];
    const float* edge_w = (const float*)d_in[1];
    const int*   dim_p  = (const int*)d_in[5];
    float*       out    = (float*)d_out;

    const int E = in_sizes[0] / 2;
    const int F = in_sizes[1] / E;           // 64
    const int N = out_size / F;              // 50000
    const int NB = (N + 255) / 256;          // scan blocks (196)

    // workspace: counts[N] | offsets[N+1] | cursor[N] | perm[E] | partials[256]
    const size_t need = ((size_t)3 * N + 1 + (size_t)E + 256) * sizeof(int);
    if (ws_size < need || NB > 256) {
        hipMemsetAsync(d_out, 0, (size_t)out_size * sizeof(float), stream);
        atomic_kernel<<<2048, 256, 0, stream>>>(edge, edge_w, dim_p, out, E);
        return;
    }

    int* counts   = (int*)d_ws;
    int* offsets  = counts + N;
    int* cursor   = offsets + N + 1;
    int* perm     = cursor + N;
    int* partials = perm + E;

    const int block = 256;
    const int gridE = min(2048, (E + block - 1) / block);

    zero_kernel<<<NB, block, 0, stream>>>(counts, N);
    hist_kernel<<<gridE, block, 0, stream>>>(edge, dim_p, counts, E);
    scanA_kernel<<<NB, block, 0, stream>>>(counts, offsets, partials, N);
    scanB_kernel<<<1, block, 0, stream>>>(partials, NB);
    scanC_kernel<<<NB, block, 0, stream>>>(offsets, cursor, partials, N, E);
    scatter_kernel<<<gridE, block, 0, stream>>>(edge, dim_p, cursor, perm, E);

    const int gridN = (N + 3) / 4;           // 4 nodes (waves) per block
    gather_kernel<<<gridN, block, 0, stream>>>(edge_w, offsets, perm, out, N);
}

// Round 5
// 163.376 us; speedup vs baseline: 6.5438x; 1.3873x over previous
//
#include <hip/hip_runtime.h>
#include <hip/hip_bf16.h>

// Segment-sum via CSR build + atomic-free gather.
// out[seg, f] = sum over edges e with edge[row][e]==seg of edge_w[e, f].
// row = 0 if dim==1 else 1 (read on device).
//
// R4: (1) hist+scatter collapsed to rank_hist (atomic, writes rank[e]
// coalesced into d_out-as-scratch) + place (atomic-free scattered write):
// halves atomic count, drops cursor. (2) scanB fused into scanC.
// (3) gather: nontemporal row loads + 2-deep unroll.

#define F_DIM 64

typedef __attribute__((ext_vector_type(4))) float f4v;

// ---------- zero counts ----------
__global__ void zero_kernel(int* __restrict__ counts, int N) {
    const int i = blockIdx.x * blockDim.x + threadIdx.x;
    if (i < N) counts[i] = 0;
}

// ---------- rank-histogram: counts[seg]++ and rank[e] = old count ----------
__global__ void rank_hist_kernel(const int* __restrict__ edge,
                                 const int* __restrict__ dim_p,
                                 int* __restrict__ counts,
                                 int* __restrict__ rank, int E) {
    const int row = (*dim_p == 1) ? 0 : 1;
    const int stride = gridDim.x * blockDim.x;
    for (int e = blockIdx.x * blockDim.x + threadIdx.x; e < E; e += stride) {
        const int seg = edge[(size_t)row * E + e];
        rank[e] = atomicAdd(&counts[seg], 1);   // coalesced rank write
    }
}

// ---------- scan A: per-block exclusive scan + block totals ----------
__global__ void scanA_kernel(const int* __restrict__ counts,
                             int* __restrict__ offsets,
                             int* __restrict__ partials, int N) {
    __shared__ int s[256];
    const int t = threadIdx.x;
    const int idx = blockIdx.x * 256 + t;
    const int v = (idx < N) ? counts[idx] : 0;
    s[t] = v;
    __syncthreads();
    for (int d = 1; d < 256; d <<= 1) {
        const int x = (t >= d) ? s[t - d] : 0;
        __syncthreads();
        s[t] += x;
        __syncthreads();
    }
    if (idx < N) offsets[idx] = s[t] - v;      // block-local exclusive
    if (t == 255) partials[blockIdx.x] = s[255];
}

// ---------- scan BC: each block scans all partials in LDS, applies ----------
__global__ void scanBC_kernel(int* __restrict__ offsets,
                              const int* __restrict__ partials,
                              int N, int E, int NB) {
    __shared__ int s[256];
    const int t = threadIdx.x;
    const int v = (t < NB) ? partials[t] : 0;
    s[t] = v;
    __syncthreads();
    for (int d = 1; d < 256; d <<= 1) {
        const int x = (t >= d) ? s[t - d] : 0;
        __syncthreads();
        s[t] += x;
        __syncthreads();
    }
    const int prefix = s[blockIdx.x] - ((blockIdx.x < NB) ? partials[blockIdx.x] : 0);
    const int idx = blockIdx.x * 256 + t;
    if (idx < N) offsets[idx] += prefix;
    if (idx == 0) offsets[N] = E;
}

// ---------- place: perm[offsets[seg] + rank[e]] = e (no atomics) ----------
__global__ void place_kernel(const int* __restrict__ edge,
                             const int* __restrict__ dim_p,
                             const int* __restrict__ offsets,
                             const int* __restrict__ rank,
                             int* __restrict__ perm, int E) {
    const int row = (*dim_p == 1) ? 0 : 1;
    const int stride = gridDim.x * blockDim.x;
    for (int e = blockIdx.x * blockDim.x + threadIdx.x; e < E; e += stride) {
        const int seg = edge[(size_t)row * E + e];
        perm[offsets[seg] + rank[e]] = e;
    }
}

// ---------- gather-reduce: one wave per node ----------
// 8 groups of 8 lanes; group g handles edges beg+grp, +8, +16, ...
// 2-deep unroll; nontemporal loads (edge_w rows are read exactly once).
__global__ __launch_bounds__(256) void gather_kernel(
    const float* __restrict__ edge_w,
    const int* __restrict__ offsets,
    const int* __restrict__ perm,
    float* __restrict__ out, int N) {
    const int node = blockIdx.x * 4 + (threadIdx.x >> 6);
    const int lane = threadIdx.x & 63;
    if (node >= N) return;
    const int beg = offsets[node];
    const int end = offsets[node + 1];
    const int grp = lane >> 3;            // 0..7 : edge slot in the 8-batch
    const int sub = (lane & 7) << 3;      // feature offset 0..56 step 8
    f4v a0 = 0.0f, a1 = 0.0f;
    int j = beg + grp;
    // 2-deep: edges j and j+8 in flight together
    while (j + 8 < end) {
        const int eA = perm[j];
        const int eB = perm[j + 8];
        const f4v* pA = reinterpret_cast<const f4v*>(edge_w + (size_t)eA * F_DIM + sub);
        const f4v* pB = reinterpret_cast<const f4v*>(edge_w + (size_t)eB * F_DIM + sub);
        const f4v u0 = __builtin_nontemporal_load(pA);
        const f4v u1 = __builtin_nontemporal_load(pA + 1);
        const f4v w0 = __builtin_nontemporal_load(pB);
        const f4v w1 = __builtin_nontemporal_load(pB + 1);
        a0 += u0; a1 += u1;
        a0 += w0; a1 += w1;
        j += 16;
    }
    if (j < end) {
        const int eA = perm[j];
        const f4v* pA = reinterpret_cast<const f4v*>(edge_w + (size_t)eA * F_DIM + sub);
        a0 += __builtin_nontemporal_load(pA);
        a1 += __builtin_nontemporal_load(pA + 1);
    }
    // fold the 8 edge-groups (lanes l, l^8, l^16, ... share feature cols)
    #pragma unroll
    for (int m = 8; m < 64; m <<= 1) {
        a0.x += __shfl_xor(a0.x, m); a0.y += __shfl_xor(a0.y, m);
        a0.z += __shfl_xor(a0.z, m); a0.w += __shfl_xor(a0.w, m);
        a1.x += __shfl_xor(a1.x, m); a1.y += __shfl_xor(a1.y, m);
        a1.z += __shfl_xor(a1.z, m); a1.w += __shfl_xor(a1.w, m);
    }
    if (grp == 0) {
        float* o = out + (size_t)node * F_DIM + sub;
        *reinterpret_cast<f4v*>(o)     = a0;
        *reinterpret_cast<f4v*>(o + 4) = a1;
    }
}

// ---------- fallback: direct atomic scatter ----------
__global__ void atomic_kernel(const int* __restrict__ edge,
                              const float* __restrict__ edge_w,
                              const int* __restrict__ dim_p,
                              float* __restrict__ out, int E) {
    const int row = (*dim_p == 1) ? 0 : 1;
    const long long total = (long long)E * 16;
    const long long stride = (long long)gridDim.x * blockDim.x;
    for (long long i = (long long)blockIdx.x * blockDim.x + threadIdx.x;
         i < total; i += stride) {
        const int e = (int)(i >> 4);
        const int c = ((int)i & 15) << 2;
        const int seg = edge[(long long)row * E + e];
        const float4 v = *reinterpret_cast<const float4*>(
            edge_w + (long long)e * F_DIM + c);
        float* o = out + (long long)seg * F_DIM + c;
        atomicAdd(o + 0, v.x);
        atomicAdd(o + 1, v.y);
        atomicAdd(o + 2, v.z);
        atomicAdd(o + 3, v.w);
    }
}

extern "C" void kernel_launch(void* const* d_in, const int* in_sizes, int n_in,
                              void* d_out, int out_size, void* d_ws, size_t ws_size,
                              hipStream_t stream) {
    const int*   edge   = (const int*)d_in[0];
    const float* edge_w = (const float*)d_in[1];
    const int*   dim_p  = (const int*)d_in[5];
    float*       out    = (float*)d_out;

    const int E = in_sizes[0] / 2;
    const int F = in_sizes[1] / E;           // 64
    const int N = out_size / F;              // 50000
    const int NB = (N + 255) / 256;          // scan blocks (196)

    // workspace: counts[N] | offsets[N+1] | perm[E] | partials[256]
    // rank[E] lives in d_out (used as int scratch, fully overwritten by gather)
    const size_t need = ((size_t)2 * N + 1 + (size_t)E + 256) * sizeof(int);
    const bool rank_fits = (size_t)E <= (size_t)out_size;  // rank in d_out
    if (ws_size < need || NB > 256 || !rank_fits) {
        hipMemsetAsync(d_out, 0, (size_t)out_size * sizeof(float), stream);
        atomic_kernel<<<2048, 256, 0, stream>>>(edge, edge_w, dim_p, out, E);
        return;
    }

    int* counts   = (int*)d_ws;
    int* offsets  = counts + N;
    int* perm     = offsets + N + 1;
    int* partials = perm + E;
    int* rank     = (int*)d_out;             // scratch; overwritten by gather

    const int block = 256;
    const int gridE = min(2048, (E + block - 1) / block);

    zero_kernel<<<NB, block, 0, stream>>>(counts, N);
    rank_hist_kernel<<<gridE, block, 0, stream>>>(edge, dim_p, counts, rank, E);
    scanA_kernel<<<NB, block, 0, stream>>>(counts, offsets, partials, N);
    scanBC_kernel<<<NB, block, 0, stream>>>(offsets, partials, N, E, NB);
    place_kernel<<<gridE, block, 0, stream>>>(edge, dim_p, offsets, rank, perm, E);

    const int gridN = (N + 3) / 4;           // 4 nodes (waves) per block
    gather_kernel<<<gridN, block, 0, stream>>>(edge_w, offsets, perm, out, N);
}

// Round 6
// 160.575 us; speedup vs baseline: 6.6579x; 1.0174x over previous
//
#include <hip/hip_runtime.h>
#include <hip/hip_bf16.h>

// Segment-sum via CSR build + atomic-free gather.
// out[seg, f] = sum over edges e with edge[row][e]==seg of edge_w[e, f].
// row = 0 if dim==1 else 1 (read on device).
//
// R5: build-side only (gather identical to R4 for attribution):
//  - 8-way replicated histogram: r=(e>>8)&7, counts8[r*N+seg]. Cuts per-line
//    atomic serialization ~8x. scanA folds replicas + writes per-replica
//    exclusive prefixes back into counts8.
//  - int4-vectorized edge reads / rank writes in rank_hist and place.

#define F_DIM 64

typedef __attribute__((ext_vector_type(4))) float f4v;

// ---------- zero counts ----------
__global__ void zero_kernel(int* __restrict__ p, int n) {
    const int i = blockIdx.x * blockDim.x + threadIdx.x;
    if (i < n) p[i] = 0;
}

// ---------- rank-histogram: counts8[r*N+seg]++, rank[e] = old ----------
template <int R>
__global__ void rank_hist_kernel(const int* __restrict__ edge,
                                 const int* __restrict__ dim_p,
                                 int* __restrict__ counts8,
                                 int* __restrict__ rank, int E, int N) {
    const int row = (*dim_p == 1) ? 0 : 1;
    const int* er = edge + (size_t)row * E;
    const int stride = gridDim.x * blockDim.x;
    if ((E & 3) == 0) {
        const int nvec = E >> 2;
        const int4* er4 = reinterpret_cast<const int4*>(er);
        int4* rank4 = reinterpret_cast<int4*>(rank);
        for (int v = blockIdx.x * blockDim.x + threadIdx.x; v < nvec; v += stride) {
            const int4 ev = er4[v];
            const int r = (v >> 6) & (R - 1);      // e=4v -> (e>>8)&(R-1)
            int* cb = counts8 + (size_t)r * N;
            int4 rk;
            rk.x = atomicAdd(&cb[ev.x], 1);
            rk.y = atomicAdd(&cb[ev.y], 1);
            rk.z = atomicAdd(&cb[ev.z], 1);
            rk.w = atomicAdd(&cb[ev.w], 1);
            rank4[v] = rk;
        }
    } else {
        for (int e = blockIdx.x * blockDim.x + threadIdx.x; e < E; e += stride) {
            const int r = (e >> 8) & (R - 1);
            rank[e] = atomicAdd(&counts8[(size_t)r * N + er[e]], 1);
        }
    }
}

// ---------- scan A: fold replicas, per-block scan, replica prefixes ----------
template <int R>
__global__ void scanA_kernel(int* __restrict__ counts8,
                             int* __restrict__ offsets,
                             int* __restrict__ partials, int N) {
    __shared__ int s[256];
    const int t = threadIdx.x;
    const int idx = blockIdx.x * 256 + t;
    int c[R];
    int tot = 0;
    if (idx < N) {
        #pragma unroll
        for (int r = 0; r < R; ++r) { c[r] = counts8[(size_t)r * N + idx]; tot += c[r]; }
    }
    s[t] = tot;
    __syncthreads();
    for (int d = 1; d < 256; d <<= 1) {
        const int x = (t >= d) ? s[t - d] : 0;
        __syncthreads();
        s[t] += x;
        __syncthreads();
    }
    if (idx < N) {
        offsets[idx] = s[t] - tot;              // block-local exclusive
        int run = 0;
        #pragma unroll
        for (int r = 0; r < R; ++r) {           // per-replica exclusive prefix
            counts8[(size_t)r * N + idx] = run;
            run += c[r];
        }
    }
    if (t == 255) partials[blockIdx.x] = s[255];
}

// ---------- scan BC: each block scans all partials in LDS, applies ----------
__global__ void scanBC_kernel(int* __restrict__ offsets,
                              const int* __restrict__ partials,
                              int N, int E, int NB) {
    __shared__ int s[256];
    const int t = threadIdx.x;
    const int v = (t < NB) ? partials[t] : 0;
    s[t] = v;
    __syncthreads();
    for (int d = 1; d < 256; d <<= 1) {
        const int x = (t >= d) ? s[t - d] : 0;
        __syncthreads();
        s[t] += x;
        __syncthreads();
    }
    const int prefix = s[blockIdx.x] - ((blockIdx.x < NB) ? partials[blockIdx.x] : 0);
    const int idx = blockIdx.x * 256 + t;
    if (idx < N) offsets[idx] += prefix;
    if (idx == 0) offsets[N] = E;
}

// ---------- place: perm[offsets[seg]+replicaPrefix+rank] = e ----------
template <int R>
__global__ void place_kernel(const int* __restrict__ edge,
                             const int* __restrict__ dim_p,
                             const int* __restrict__ offsets,
                             const int* __restrict__ counts8,  // replica prefixes
                             const int* __restrict__ rank,
                             int* __restrict__ perm, int E, int N) {
    const int row = (*dim_p == 1) ? 0 : 1;
    const int* er = edge + (size_t)row * E;
    const int stride = gridDim.x * blockDim.x;
    if ((E & 3) == 0) {
        const int nvec = E >> 2;
        const int4* er4 = reinterpret_cast<const int4*>(er);
        const int4* rank4 = reinterpret_cast<const int4*>(rank);
        for (int v = blockIdx.x * blockDim.x + threadIdx.x; v < nvec; v += stride) {
            const int4 ev = er4[v];
            const int4 rk = rank4[v];
            const int r = (v >> 6) & (R - 1);
            const int* cb = counts8 + (size_t)r * N;
            const int e = v << 2;
            perm[offsets[ev.x] + cb[ev.x] + rk.x] = e + 0;
            perm[offsets[ev.y] + cb[ev.y] + rk.y] = e + 1;
            perm[offsets[ev.z] + cb[ev.z] + rk.z] = e + 2;
            perm[offsets[ev.w] + cb[ev.w] + rk.w] = e + 3;
        }
    } else {
        for (int e = blockIdx.x * blockDim.x + threadIdx.x; e < E; e += stride) {
            const int r = (e >> 8) & (R - 1);
            const int seg = er[e];
            perm[offsets[seg] + counts8[(size_t)r * N + seg] + rank[e]] = e;
        }
    }
}

// ---------- gather-reduce: one wave per node (identical to R4) ----------
__global__ __launch_bounds__(256) void gather_kernel(
    const float* __restrict__ edge_w,
    const int* __restrict__ offsets,
    const int* __restrict__ perm,
    float* __restrict__ out, int N) {
    const int node = blockIdx.x * 4 + (threadIdx.x >> 6);
    const int lane = threadIdx.x & 63;
    if (node >= N) return;
    const int beg = offsets[node];
    const int end = offsets[node + 1];
    const int grp = lane >> 3;            // 0..7 : edge slot in the 8-batch
    const int sub = (lane & 7) << 3;      // feature offset 0..56 step 8
    f4v a0 = 0.0f, a1 = 0.0f;
    int j = beg + grp;
    while (j + 8 < end) {
        const int eA = perm[j];
        const int eB = perm[j + 8];
        const f4v* pA = reinterpret_cast<const f4v*>(edge_w + (size_t)eA * F_DIM + sub);
        const f4v* pB = reinterpret_cast<const f4v*>(edge_w + (size_t)eB * F_DIM + sub);
        const f4v u0 = __builtin_nontemporal_load(pA);
        const f4v u1 = __builtin_nontemporal_load(pA + 1);
        const f4v w0 = __builtin_nontemporal_load(pB);
        const f4v w1 = __builtin_nontemporal_load(pB + 1);
        a0 += u0; a1 += u1;
        a0 += w0; a1 += w1;
        j += 16;
    }
    if (j < end) {
        const int eA = perm[j];
        const f4v* pA = reinterpret_cast<const f4v*>(edge_w + (size_t)eA * F_DIM + sub);
        a0 += __builtin_nontemporal_load(pA);
        a1 += __builtin_nontemporal_load(pA + 1);
    }
    #pragma unroll
    for (int m = 8; m < 64; m <<= 1) {
        a0.x += __shfl_xor(a0.x, m); a0.y += __shfl_xor(a0.y, m);
        a0.z += __shfl_xor(a0.z, m); a0.w += __shfl_xor(a0.w, m);
        a1.x += __shfl_xor(a1.x, m); a1.y += __shfl_xor(a1.y, m);
        a1.z += __shfl_xor(a1.z, m); a1.w += __shfl_xor(a1.w, m);
    }
    if (grp == 0) {
        float* o = out + (size_t)node * F_DIM + sub;
        *reinterpret_cast<f4v*>(o)     = a0;
        *reinterpret_cast<f4v*>(o + 4) = a1;
    }
}

// ---------- fallback: direct atomic scatter ----------
__global__ void atomic_kernel(const int* __restrict__ edge,
                              const float* __restrict__ edge_w,
                              const int* __restrict__ dim_p,
                              float* __restrict__ out, int E) {
    const int row = (*dim_p == 1) ? 0 : 1;
    const long long total = (long long)E * 16;
    const long long stride = (long long)gridDim.x * blockDim.x;
    for (long long i = (long long)blockIdx.x * blockDim.x + threadIdx.x;
         i < total; i += stride) {
        const int e = (int)(i >> 4);
        const int c = ((int)i & 15) << 2;
        const int seg = edge[(long long)row * E + e];
        const float4 v = *reinterpret_cast<const float4*>(
            edge_w + (long long)e * F_DIM + c);
        float* o = out + (long long)seg * F_DIM + c;
        atomicAdd(o + 0, v.x);
        atomicAdd(o + 1, v.y);
        atomicAdd(o + 2, v.z);
        atomicAdd(o + 3, v.w);
    }
}

extern "C" void kernel_launch(void* const* d_in, const int* in_sizes, int n_in,
                              void* d_out, int out_size, void* d_ws, size_t ws_size,
                              hipStream_t stream) {
    const int*   edge   = (const int*)d_in[0];
    const float* edge_w = (const float*)d_in[1];
    const int*   dim_p  = (const int*)d_in[5];
    float*       out    = (float*)d_out;

    const int E = in_sizes[0] / 2;
    const int F = in_sizes[1] / E;           // 64
    const int N = out_size / F;              // 50000
    const int NB = (N + 255) / 256;          // scan blocks (196)

    // ws: counts8[R*N] | offsets[N+1] | perm[E] | partials[256]; rank in d_out
    const size_t need8 = ((size_t)8 * N + N + 1 + (size_t)E + 256) * sizeof(int);
    const size_t need1 = ((size_t)1 * N + N + 1 + (size_t)E + 256) * sizeof(int);
    const bool rank_fits = (size_t)E <= (size_t)out_size;
    if (ws_size < need1 || NB > 256 || !rank_fits) {
        hipMemsetAsync(d_out, 0, (size_t)out_size * sizeof(float), stream);
        atomic_kernel<<<2048, 256, 0, stream>>>(edge, edge_w, dim_p, out, E);
        return;
    }
    const int R = (ws_size >= need8) ? 8 : 1;

    int* counts8  = (int*)d_ws;
    int* offsets  = counts8 + (size_t)R * N;
    int* perm     = offsets + N + 1;
    int* partials = perm + E;
    int* rank     = (int*)d_out;             // scratch; overwritten by gather

    const int block = 256;
    const int gridV = min(4096, (E / 4 + block - 1) / block);  // vec4 grids
    const int gridE = min(4096, (E + block - 1) / block);
    const int gridZ = (R * N + block - 1) / block;

    zero_kernel<<<gridZ, block, 0, stream>>>(counts8, R * N);
    if (R == 8) {
        rank_hist_kernel<8><<<(E & 3) ? gridE : gridV, block, 0, stream>>>(
            edge, dim_p, counts8, rank, E, N);
        scanA_kernel<8><<<NB, block, 0, stream>>>(counts8, offsets, partials, N);
        scanBC_kernel<<<NB, block, 0, stream>>>(offsets, partials, N, E, NB);
        place_kernel<8><<<(E & 3) ? gridE : gridV, block, 0, stream>>>(
            edge, dim_p, offsets, counts8, rank, perm, E, N);
    } else {
        rank_hist_kernel<1><<<(E & 3) ? gridE : gridV, block, 0, stream>>>(
            edge, dim_p, counts8, rank, E, N);
        scanA_kernel<1><<<NB, block, 0, stream>>>(counts8, offsets, partials, N);
        scanBC_kernel<<<NB, block, 0, stream>>>(offsets, partials, N, E, NB);
        place_kernel<1><<<(E & 3) ? gridE : gridV, block, 0, stream>>>(
            edge, dim_p, offsets, counts8, rank, perm, E, N);
    }

    const int gridN = (N + 3) / 4;           // 4 nodes (waves) per block
    gather_kernel<<<gridN, block, 0, stream>>>(edge_w, offsets, perm, out, N);
}

// Round 7
// 152.122 us; speedup vs baseline: 7.0279x; 1.0556x over previous
//
#include <hip/hip_runtime.h>
#include <hip/hip_bf16.h>

// Segment-sum via CSR build + atomic-free gather.
// out[seg, f] = sum over edges e with edge[row][e]==seg of edge_w[e, f].
// row = 0 if dim==1 else 1 (read on device).
//
// R6: gather-only changes (build identical to R5 for attribution):
//  - dropped __builtin_nontemporal_load: edge_w (320MB) is ~80% L3-resident
//    across replays; nt bit evicts early and forces HBM re-fetch.
//  - 4-deep predicated unroll: 4 perm loads + 8 row loads issue together
//    (invalid slots clamp to e0 = L1-hit duplicate); accumulation predicated.
//    Covers deg<=32 per 8-lane group in one iteration (deg~25 typical).

#define F_DIM 64

typedef __attribute__((ext_vector_type(4))) float f4v;

// ---------- zero counts ----------
__global__ void zero_kernel(int* __restrict__ p, int n) {
    const int i = blockIdx.x * blockDim.x + threadIdx.x;
    if (i < n) p[i] = 0;
}

// ---------- rank-histogram: counts8[r*N+seg]++, rank[e] = old ----------
template <int R>
__global__ void rank_hist_kernel(const int* __restrict__ edge,
                                 const int* __restrict__ dim_p,
                                 int* __restrict__ counts8,
                                 int* __restrict__ rank, int E, int N) {
    const int row = (*dim_p == 1) ? 0 : 1;
    const int* er = edge + (size_t)row * E;
    const int stride = gridDim.x * blockDim.x;
    if ((E & 3) == 0) {
        const int nvec = E >> 2;
        const int4* er4 = reinterpret_cast<const int4*>(er);
        int4* rank4 = reinterpret_cast<int4*>(rank);
        for (int v = blockIdx.x * blockDim.x + threadIdx.x; v < nvec; v += stride) {
            const int4 ev = er4[v];
            const int r = (v >> 6) & (R - 1);      // e=4v -> (e>>8)&(R-1)
            int* cb = counts8 + (size_t)r * N;
            int4 rk;
            rk.x = atomicAdd(&cb[ev.x], 1);
            rk.y = atomicAdd(&cb[ev.y], 1);
            rk.z = atomicAdd(&cb[ev.z], 1);
            rk.w = atomicAdd(&cb[ev.w], 1);
            rank4[v] = rk;
        }
    } else {
        for (int e = blockIdx.x * blockDim.x + threadIdx.x; e < E; e += stride) {
            const int r = (e >> 8) & (R - 1);
            rank[e] = atomicAdd(&counts8[(size_t)r * N + er[e]], 1);
        }
    }
}

// ---------- scan A: fold replicas, per-block scan, replica prefixes ----------
template <int R>
__global__ void scanA_kernel(int* __restrict__ counts8,
                             int* __restrict__ offsets,
                             int* __restrict__ partials, int N) {
    __shared__ int s[256];
    const int t = threadIdx.x;
    const int idx = blockIdx.x * 256 + t;
    int c[R];
    int tot = 0;
    if (idx < N) {
        #pragma unroll
        for (int r = 0; r < R; ++r) { c[r] = counts8[(size_t)r * N + idx]; tot += c[r]; }
    }
    s[t] = tot;
    __syncthreads();
    for (int d = 1; d < 256; d <<= 1) {
        const int x = (t >= d) ? s[t - d] : 0;
        __syncthreads();
        s[t] += x;
        __syncthreads();
    }
    if (idx < N) {
        offsets[idx] = s[t] - tot;              // block-local exclusive
        int run = 0;
        #pragma unroll
        for (int r = 0; r < R; ++r) {           // per-replica exclusive prefix
            counts8[(size_t)r * N + idx] = run;
            run += c[r];
        }
    }
    if (t == 255) partials[blockIdx.x] = s[255];
}

// ---------- scan BC: each block scans all partials in LDS, applies ----------
__global__ void scanBC_kernel(int* __restrict__ offsets,
                              const int* __restrict__ partials,
                              int N, int E, int NB) {
    __shared__ int s[256];
    const int t = threadIdx.x;
    const int v = (t < NB) ? partials[t] : 0;
    s[t] = v;
    __syncthreads();
    for (int d = 1; d < 256; d <<= 1) {
        const int x = (t >= d) ? s[t - d] : 0;
        __syncthreads();
        s[t] += x;
        __syncthreads();
    }
    const int prefix = s[blockIdx.x] - ((blockIdx.x < NB) ? partials[blockIdx.x] : 0);
    const int idx = blockIdx.x * 256 + t;
    if (idx < N) offsets[idx] += prefix;
    if (idx == 0) offsets[N] = E;
}

// ---------- place: perm[offsets[seg]+replicaPrefix+rank] = e ----------
template <int R>
__global__ void place_kernel(const int* __restrict__ edge,
                             const int* __restrict__ dim_p,
                             const int* __restrict__ offsets,
                             const int* __restrict__ counts8,  // replica prefixes
                             const int* __restrict__ rank,
                             int* __restrict__ perm, int E, int N) {
    const int row = (*dim_p == 1) ? 0 : 1;
    const int* er = edge + (size_t)row * E;
    const int stride = gridDim.x * blockDim.x;
    if ((E & 3) == 0) {
        const int nvec = E >> 2;
        const int4* er4 = reinterpret_cast<const int4*>(er);
        const int4* rank4 = reinterpret_cast<const int4*>(rank);
        for (int v = blockIdx.x * blockDim.x + threadIdx.x; v < nvec; v += stride) {
            const int4 ev = er4[v];
            const int4 rk = rank4[v];
            const int r = (v >> 6) & (R - 1);
            const int* cb = counts8 + (size_t)r * N;
            const int e = v << 2;
            perm[offsets[ev.x] + cb[ev.x] + rk.x] = e + 0;
            perm[offsets[ev.y] + cb[ev.y] + rk.y] = e + 1;
            perm[offsets[ev.z] + cb[ev.z] + rk.z] = e + 2;
            perm[offsets[ev.w] + cb[ev.w] + rk.w] = e + 3;
        }
    } else {
        for (int e = blockIdx.x * blockDim.x + threadIdx.x; e < E; e += stride) {
            const int r = (e >> 8) & (R - 1);
            const int seg = er[e];
            perm[offsets[seg] + counts8[(size_t)r * N + seg] + rank[e]] = e;
        }
    }
}

// ---------- gather-reduce: one wave per node ----------
// 8 groups of 8 lanes; group g handles edges beg+g, +8, +16, ...
// 4-deep predicated unroll: all loads issue together; invalid slots load
// row e0 again (L1 hit) and their adds are predicated off.
__global__ __launch_bounds__(256) void gather_kernel(
    const float* __restrict__ edge_w,
    const int* __restrict__ offsets,
    const int* __restrict__ perm,
    float* __restrict__ out, int N) {
    const int node = blockIdx.x * 4 + (threadIdx.x >> 6);
    const int lane = threadIdx.x & 63;
    if (node >= N) return;
    const int beg = offsets[node];
    const int end = offsets[node + 1];
    const int grp = lane >> 3;            // 0..7 : edge slot in the 8-batch
    const int sub = (lane & 7) << 3;      // feature offset 0..56 step 8
    f4v a0 = 0.0f, a1 = 0.0f;
    int j = beg + grp;
    while (j < end) {
        const int j1 = j + 8, j2 = j + 16, j3 = j + 24;
        const int e0 = perm[j];
        const int e1 = (j1 < end) ? perm[j1] : e0;
        const int e2 = (j2 < end) ? perm[j2] : e0;
        const int e3 = (j3 < end) ? perm[j3] : e0;
        const f4v* p0 = reinterpret_cast<const f4v*>(edge_w + (size_t)e0 * F_DIM + sub);
        const f4v* p1 = reinterpret_cast<const f4v*>(edge_w + (size_t)e1 * F_DIM + sub);
        const f4v* p2 = reinterpret_cast<const f4v*>(edge_w + (size_t)e2 * F_DIM + sub);
        const f4v* p3 = reinterpret_cast<const f4v*>(edge_w + (size_t)e3 * F_DIM + sub);
        const f4v u0 = p0[0], u1 = p0[1];
        const f4v v0 = p1[0], v1 = p1[1];
        const f4v w0 = p2[0], w1 = p2[1];
        const f4v x0 = p3[0], x1 = p3[1];
        a0 += u0; a1 += u1;
        if (j1 < end) { a0 += v0; a1 += v1; }
        if (j2 < end) { a0 += w0; a1 += w1; }
        if (j3 < end) { a0 += x0; a1 += x1; }
        j += 32;
    }
    // fold the 8 edge-groups (lanes l, l^8, l^16, ... share feature cols)
    #pragma unroll
    for (int m = 8; m < 64; m <<= 1) {
        a0.x += __shfl_xor(a0.x, m); a0.y += __shfl_xor(a0.y, m);
        a0.z += __shfl_xor(a0.z, m); a0.w += __shfl_xor(a0.w, m);
        a1.x += __shfl_xor(a1.x, m); a1.y += __shfl_xor(a1.y, m);
        a1.z += __shfl_xor(a1.z, m); a1.w += __shfl_xor(a1.w, m);
    }
    if (grp == 0) {
        float* o = out + (size_t)node * F_DIM + sub;
        *reinterpret_cast<f4v*>(o)     = a0;
        *reinterpret_cast<f4v*>(o + 4) = a1;
    }
}

// ---------- fallback: direct atomic scatter ----------
__global__ void atomic_kernel(const int* __restrict__ edge,
                              const float* __restrict__ edge_w,
                              const int* __restrict__ dim_p,
                              float* __restrict__ out, int E) {
    const int row = (*dim_p == 1) ? 0 : 1;
    const long long total = (long long)E * 16;
    const long long stride = (long long)gridDim.x * blockDim.x;
    for (long long i = (long long)blockIdx.x * blockDim.x + threadIdx.x;
         i < total; i += stride) {
        const int e = (int)(i >> 4);
        const int c = ((int)i & 15) << 2;
        const int seg = edge[(long long)row * E + e];
        const float4 v = *reinterpret_cast<const float4*>(
            edge_w + (long long)e * F_DIM + c);
        float* o = out + (long long)seg * F_DIM + c;
        atomicAdd(o + 0, v.x);
        atomicAdd(o + 1, v.y);
        atomicAdd(o + 2, v.z);
        atomicAdd(o + 3, v.w);
    }
}

extern "C" void kernel_launch(void* const* d_in, const int* in_sizes, int n_in,
                              void* d_out, int out_size, void* d_ws, size_t ws_size,
                              hipStream_t stream) {
    const int*   edge   = (const int*)d_in[0];
    const float* edge_w = (const float*)d_in[1];
    const int*   dim_p  = (const int*)d_in[5];
    float*       out    = (float*)d_out;

    const int E = in_sizes[0] / 2;
    const int F = in_sizes[1] / E;           // 64
    const int N = out_size / F;              // 50000
    const int NB = (N + 255) / 256;          // scan blocks (196)

    // ws: counts8[R*N] | offsets[N+1] | perm[E] | partials[256]; rank in d_out
    const size_t need8 = ((size_t)8 * N + N + 1 + (size_t)E + 256) * sizeof(int);
    const size_t need1 = ((size_t)1 * N + N + 1 + (size_t)E + 256) * sizeof(int);
    const bool rank_fits = (size_t)E <= (size_t)out_size;
    if (ws_size < need1 || NB > 256 || !rank_fits) {
        hipMemsetAsync(d_out, 0, (size_t)out_size * sizeof(float), stream);
        atomic_kernel<<<2048, 256, 0, stream>>>(edge, edge_w, dim_p, out, E);
        return;
    }
    const int R = (ws_size >= need8) ? 8 : 1;

    int* counts8  = (int*)d_ws;
    int* offsets  = counts8 + (size_t)R * N;
    int* perm     = offsets + N + 1;
    int* partials = perm + E;
    int* rank     = (int*)d_out;             // scratch; overwritten by gather

    const int block = 256;
    const int gridV = min(4096, (E / 4 + block - 1) / block);  // vec4 grids
    const int gridE = min(4096, (E + block - 1) / block);
    const int gridZ = (R * N + block - 1) / block;

    zero_kernel<<<gridZ, block, 0, stream>>>(counts8, R * N);
    if (R == 8) {
        rank_hist_kernel<8><<<(E & 3) ? gridE : gridV, block, 0, stream>>>(
            edge, dim_p, counts8, rank, E, N);
        scanA_kernel<8><<<NB, block, 0, stream>>>(counts8, offsets, partials, N);
        scanBC_kernel<<<NB, block, 0, stream>>>(offsets, partials, N, E, NB);
        place_kernel<8><<<(E & 3) ? gridE : gridV, block, 0, stream>>>(
            edge, dim_p, offsets, counts8, rank, perm, E, N);
    } else {
        rank_hist_kernel<1><<<(E & 3) ? gridE : gridV, block, 0, stream>>>(
            edge, dim_p, counts8, rank, E, N);
        scanA_kernel<1><<<NB, block, 0, stream>>>(counts8, offsets, partials, N);
        scanBC_kernel<<<NB, block, 0, stream>>>(offsets, partials, N, E, NB);
        place_kernel<1><<<(E & 3) ? gridE : gridV, block, 0, stream>>>(
            edge, dim_p, offsets, counts8, rank, perm, E, N);
    }

    const int gridN = (N + 3) / 4;           // 4 nodes (waves) per block
    gather_kernel<<<gridN, block, 0, stream>>>(edge_w, offsets, perm, out, N);
}